// Round 10
// baseline (160.186 us; speedup 1.0000x reference)
//
#include <hip/hip_runtime.h>
#include <hip/hip_cooperative_groups.h>
#include <hip/hip_bf16.h>
#include <math.h>

namespace cg = cooperative_groups;

#define SEQ 4096
#define HD  64
#define NBATCH 4

#define EM1   1.71828182845904523536f
#define INVD5 (1.0f/(4096.f + 5.f*EM1))
#define INVD4 (1.0f/(4096.f + 4.f*EM1))
#define INVD3 (1.0f/(4096.f + 3.f*EM1))

typedef __attribute__((ext_vector_type(8))) short short8;
typedef __attribute__((ext_vector_type(4))) float f32x4;

__device__ __forceinline__ f32x4 mfma16(short8 a, short8 b, f32x4 c) {
    return __builtin_amdgcn_mfma_f32_16x16x32_bf16(a, b, c, 0, 0, 0);
}

__device__ __forceinline__ short rne(float x) {       // RNE float->bf16 bits
    unsigned u = __float_as_uint(x);
    u += 0x7fffu + ((u >> 16) & 1u);
    return (short)(u >> 16);
}

__device__ __forceinline__ short8 pack8(float4 a, float4 b) {
    short8 r;
    r[0] = rne(a.x); r[1] = rne(a.y); r[2] = rne(a.z); r[3] = rne(a.w);
    r[4] = rne(b.x); r[5] = rne(b.y); r[6] = rne(b.z); r[7] = rne(b.w);
    return r;
}

__device__ __forceinline__ float blo(unsigned v) { return __uint_as_float(v << 16); }
__device__ __forceinline__ float bhi(unsigned v) { return __uint_as_float(v & 0xffff0000u); }
__device__ __forceinline__ float b2f(__hip_bfloat16 h) { return __bfloat162float(h); }

// ---------------------------------------------------------------------------
// ONE cooperative kernel, 256 blocks x 256 thr (1 block/CU), 2 grid syncs.
// ---------------------------------------------------------------------------
__global__ __launch_bounds__(256) void fused_kernel(
    const float* __restrict__ feat,
    const float* __restrict__ Wq, const float* __restrict__ bq,
    const float* __restrict__ Wk, const float* __restrict__ bk,
    const float* __restrict__ Wv, const float* __restrict__ bv,
    __hip_bfloat16* __restrict__ qsb, __hip_bfloat16* __restrict__ ktb,
    __hip_bfloat16* __restrict__ vtb,
    float* __restrict__ kpart, float* __restrict__ vpart,
    float* __restrict__ Mfull, float* __restrict__ Mcorr,
    float* __restrict__ mktotF, float* __restrict__ VtotF,
    float* __restrict__ out)
{
    cg::grid_group grid = cg::this_grid();

    __shared__ __hip_bfloat16 tscr[64 * 72];   // proj transpose / phase-C MT
    __shared__ float kred[4][64];
    __shared__ float scr[4][64];
    __shared__ float ktl[64], vtl[64];
    __shared__ float lc[4][64], vv_e[4][64];

    const int tid  = threadIdx.x;
    const int blk  = blockIdx.x;
    const int wave = tid >> 6, lane = tid & 63;
    const int quad = lane >> 4, ln = lane & 15;

    // ================= Phase A: projections (all 256 blocks, 64 rows) ======
    {
        const int R0 = blk * 64;
        const int b  = R0 >> 12;
        const int t0 = R0 & (SEQ - 1);

        short8 af0, af1;
        {
            const float* fp = feat + (size_t)(R0 + wave * 16 + ln) * HD + quad * 8;
            af0 = pack8(*(const float4*)(fp),      *(const float4*)(fp + 4));
            af1 = pack8(*(const float4*)(fp + 32), *(const float4*)(fp + 36));
        }

        const float* Ws[3] = {Wq, Wk, Wv};
        const float* Bs[3] = {bq, bk, bv};

        #pragma unroll
        for (int m = 0; m < 3; ++m) {
            const float* W = Ws[m];
            const float* bias = Bs[m];
            #pragma unroll
            for (int ct = 0; ct < 4; ++ct) {
                const int col = ct * 16 + ln;
                const float* wp = W + (size_t)col * HD + quad * 8;
                short8 b0 = pack8(*(const float4*)(wp),      *(const float4*)(wp + 4));
                short8 b1 = pack8(*(const float4*)(wp + 32), *(const float4*)(wp + 36));
                f32x4 c = {};
                c = mfma16(af0, b0, c);
                c = mfma16(af1, b1, c);
                const float bl = bias[col];

                if (m == 0) {
                    #pragma unroll
                    for (int r = 0; r < 4; ++r) {
                        __hip_bfloat16 hv;
                        *(short*)&hv = rne((c[r] + bl) * 0.125f);
                        qsb[(size_t)(R0 + wave * 16 + quad * 4 + r) * HD + col] = hv;
                    }
                } else {
                    float tot = c[0] + c[1] + c[2] + c[3];
                    tot += __shfl_xor(tot, 16);
                    tot += __shfl_xor(tot, 32);
                    if (quad == 0) kred[wave][col] = tot;
                    #pragma unroll
                    for (int r = 0; r < 4; ++r)
                        *(short*)&tscr[col * 72 + wave * 16 + quad * 4 + r] =
                            rne(c[r] + bl);
                }
            }
            if (m > 0) {
                __syncthreads();
                if (tid < 64)
                    ((m == 1) ? kpart : vpart)[(size_t)blk * 64 + tid] =
                        kred[0][tid] + kred[1][tid] + kred[2][tid] + kred[3][tid]
                        + 64.f * bias[tid];
                __hip_bfloat16* dst = (m == 1) ? ktb : vtb;
                #pragma unroll
                for (int i = 0; i < 2; ++i) {
                    const int tsk = i * 256 + tid;     // 512 tasks: 64 h x 8 chunks
                    const int hh = tsk >> 3, c8 = tsk & 7;
                    short8 vv = *(const short8*)&tscr[hh * 72 + c8 * 8];
                    *(short8*)(dst + ((size_t)(b * HD + hh)) * SEQ + t0 + c8 * 8) = vv;
                }
                __syncthreads();
            }
        }

        // zero Mfull (workspace is poisoned)
        if (blk < 16) {
            float4 z = make_float4(0.f, 0.f, 0.f, 0.f);
            *(float4*)&Mfull[blk * 1024 + tid * 4] = z;
        }
    }

    grid.sync();

    // ================= Phase B =============================================
    if (blk < 64) {
        // ---- register-direct GEMM: M[h1][h2] += sum_t k[t][h1]*locv5[t][h2]
        const int b = blk >> 4, strip = (blk >> 2) & 3, kslab = blk & 3;
        const __hip_bfloat16* krow = ktb + (size_t)(b * 64 + strip * 16 + ln) * SEQ;
        f32x4 acc[4] = {};
        const int tbase = kslab * 1024 + wave * 256;

        for (int c8 = 0; c8 < 8; ++c8) {
            const int t0c = tbase + c8 * 32;
            const int t0q = t0c + quad * 8;
            short8 a = *(const short8*)(krow + t0q);
            const bool edge = (t0c == 0) || (t0c == SEQ - 32);
            #pragma unroll
            for (int ct = 0; ct < 4; ++ct) {
                const __hip_bfloat16* vrow = vtb + (size_t)(b * 64 + ct * 16 + ln) * SEQ;
                float w[12];
                if (!edge) {
                    const unsigned* v32 = (const unsigned*)vrow + ((t0q - 2) >> 1);
                    #pragma unroll
                    for (int j = 0; j < 6; ++j) {
                        const unsigned u = v32[j];
                        w[2 * j]     = blo(u);
                        w[2 * j + 1] = bhi(u);
                    }
                } else {
                    #pragma unroll
                    for (int j = 0; j < 12; ++j) {
                        const int gt = t0q - 2 + j;
                        w[j] = (gt >= 0 && gt < SEQ) ? b2f(vrow[gt]) : 0.f;
                    }
                }
                short8 bb;
                #pragma unroll
                for (int i = 0; i < 8; ++i)
                    bb[i] = rne(w[i] + w[i+1] + w[i+2] + w[i+3] + w[i+4]);
                acc[ct] = mfma16(a, bb, acc[ct]);
            }
        }
        #pragma unroll
        for (int ct = 0; ct < 4; ++ct)
            #pragma unroll
            for (int r = 0; r < 4; ++r)
                atomicAdd(&Mfull[b * 4096 + (strip * 16 + quad * 4 + r) * 64
                                 + ct * 16 + ln], acc[ct][r]);
    } else if (blk < 80) {
        // ---- corrections: ktot/vtot reductions + mktot + Vtot + Mcorr
        const int rb = blk - 64, b = rb >> 2, task = rb & 3;
        const int g = tid >> 6, h = tid & 63;
        {
            float kp = 0.f, vp = 0.f;
            for (int j = 0; j < 16; ++j) {
                kp += kpart[(size_t)(b * 64 + g * 16 + j) * 64 + h];
                vp += vpart[(size_t)(b * 64 + g * 16 + j) * 64 + h];
            }
            scr[g][h] = kp;
            kred[g][h] = vp;
        }
        __syncthreads();
        if (tid < 64) {
            ktl[tid] = scr[0][tid] + scr[1][tid] + scr[2][tid] + scr[3][tid];
            vtl[tid] = kred[0][tid] + kred[1][tid] + kred[2][tid] + kred[3][tid];
        }
        __syncthreads();

        if (task == 0 && tid < 64) {
            const int hh = tid;
            const float kt = ktl[hh];
            const __hip_bfloat16* kr = ktb + (size_t)(b * 64 + hh) * SEQ;
            const float e0 = b2f(kr[0]), e1 = b2f(kr[1]), e2 = b2f(kr[2]), e3 = b2f(kr[3]);
            const float f0 = b2f(kr[SEQ-4]), f1 = b2f(kr[SEQ-3]);
            const float f2 = b2f(kr[SEQ-2]), f3 = b2f(kr[SEQ-1]);
            const float Sint = 5.f*kt - 4.f*e0 - 3.f*e1 - 2.f*e2 - e3
                             - f0 - 2.f*f1 - 3.f*f2 - 4.f*f3;
            const float SlocD = Sint * INVD5
                              + (e0+e1+e2 + f1+f2+f3) * INVD3
                              + (e0+e1+e2+e3 + f0+f1+f2+f3) * INVD4;
            mktotF[b * 64 + hh] =
                kt * (4092.f*INVD5 + 2.f*INVD4 + 2.f*INVD3) + EM1 * SlocD;
        } else if (task == 1 && tid < 64) {
            VtotF[b * 64 + tid] = vtl[tid];
        } else if (task == 2) {
            if (tid < 64) {
                const int hh = tid;
                const __hip_bfloat16* kr = ktb + (size_t)(b * 64 + hh) * SEQ;
                const float e0 = b2f(kr[0]), e1 = b2f(kr[1]), e2 = b2f(kr[2]), e3 = b2f(kr[3]);
                const float f0 = b2f(kr[SEQ-4]), f1 = b2f(kr[SEQ-3]);
                const float f2 = b2f(kr[SEQ-2]), f3 = b2f(kr[SEQ-1]);
                lc[0][hh] = e0 + e1 + e2;
                lc[1][hh] = e0 + e1 + e2 + e3;
                lc[2][hh] = f0 + f1 + f2 + f3;
                lc[3][hh] = f1 + f2 + f3;
                const __hip_bfloat16* vr = vtb + (size_t)(b * 64 + hh) * SEQ;
                vv_e[0][hh] = b2f(vr[0]);
                vv_e[1][hh] = b2f(vr[1]);
                vv_e[2][hh] = b2f(vr[SEQ-2]);
                vv_e[3][hh] = b2f(vr[SEQ-1]);
            }
            __syncthreads();
            const float dd3 = INVD3 - INVD5, dd4 = INVD4 - INVD5;
            const int h1 = tid >> 2;
            const float l0 = lc[0][h1], l1 = lc[1][h1], l2 = lc[2][h1], l3 = lc[3][h1];
            const float kt1 = ktl[h1];
            #pragma unroll
            for (int j = 0; j < 16; ++j) {
                const int h2 = (tid & 3) * 16 + j;
                const float VD = INVD5 * vtl[h2]
                               + dd3 * (vv_e[0][h2] + vv_e[3][h2])
                               + dd4 * (vv_e[1][h2] + vv_e[2][h2]);
                Mcorr[(size_t)(b * 64 + h1) * 64 + h2] =
                    EM1 * (dd3 * (l0 * vv_e[0][h2] + l3 * vv_e[3][h2])
                         + dd4 * (l1 * vv_e[1][h2] + l2 * vv_e[2][h2]))
                    + kt1 * VD;
            }
        }
    }

    grid.sync();

    // ================= Phase C: out (all 256 blocks, 64 rows) ==============
    {
        const int R0 = blk * 64;
        const int b  = R0 >> 12;

        // build MT bf16 in LDS: MT[h2][h1] = scale*Mfull[h1][h2] + Mcorr
        {
            const int h2 = tid & 63, seg = tid >> 6;
            #pragma unroll
            for (int j = 0; j < 16; ++j) {
                const int h1 = seg * 16 + j;
                const float m = (EM1 * INVD5) * Mfull[b * 4096 + h1 * 64 + h2]
                              + Mcorr[(size_t)(b * 64 + h1) * 64 + h2];
                *(short*)&tscr[h2 * 72 + h1] = rne(m);
            }
        }
        __syncthreads();

        short8 qa0, qa1;
        {
            const __hip_bfloat16* qp = qsb + (size_t)(R0 + wave * 16 + ln) * HD + quad * 8;
            qa0 = *(const short8*)qp;
            qa1 = *(const short8*)(qp + 32);
        }
        short8 mk0, mk1;
        #pragma unroll
        for (int j = 0; j < 8; ++j) {
            mk0[j] = rne(mktotF[b * 64 + quad * 8 + j]);
            mk1[j] = rne(mktotF[b * 64 + 32 + quad * 8 + j]);
        }

        f32x4 acc[4];
        #pragma unroll
        for (int ct = 0; ct < 4; ++ct) {
            short8 b0 = *(const short8*)&tscr[(ct * 16 + ln) * 72 + quad * 8];
            short8 b1 = *(const short8*)&tscr[(ct * 16 + ln) * 72 + 32 + quad * 8];
            f32x4 c = {};
            c = mfma16(qa0, b0, c);
            c = mfma16(qa1, b1, c);
            acc[ct] = c;
        }
        f32x4 accd = {};
        accd = mfma16(qa0, mk0, accd);
        accd = mfma16(qa1, mk1, accd);     // lane-uniform across ln: den per row

        float vt[4];
        #pragma unroll
        for (int ct = 0; ct < 4; ++ct) vt[ct] = VtotF[b * 64 + ct * 16 + ln];

        float inv[4];
        #pragma unroll
        for (int r = 0; r < 4; ++r) inv[r] = 1.f / (4096.f + accd[r]);

        #pragma unroll
        for (int ct = 0; ct < 4; ++ct)
            #pragma unroll
            for (int r = 0; r < 4; ++r)
                out[(size_t)(R0 + wave * 16 + quad * 4 + r) * HD + ct * 16 + ln] =
                    (vt[ct] + acc[ct][r]) * inv[r];
    }
}

// ---------------------------------------------------------------------------
extern "C" void kernel_launch(void* const* d_in, const int* in_sizes, int n_in,
                              void* d_out, int out_size, void* d_ws, size_t ws_size,
                              hipStream_t stream)
{
    const float* feat = (const float*)d_in[0];
    const float* Wq = (const float*)d_in[1];
    const float* bq = (const float*)d_in[2];
    const float* Wk = (const float*)d_in[3];
    const float* bk = (const float*)d_in[4];
    const float* Wv = (const float*)d_in[5];
    const float* bv = (const float*)d_in[6];
    float* out = (float*)d_out;

    char* ws = (char*)d_ws;
    __hip_bfloat16* qsb    = (__hip_bfloat16*)(ws + 0);                  // 2 MB
    __hip_bfloat16* ktb    = (__hip_bfloat16*)(ws + (2u << 20));         // 2 MB
    __hip_bfloat16* vtb    = (__hip_bfloat16*)(ws + (4u << 20));         // 2 MB
    float*          kpart  = (float*)(ws + (6u << 20));                  // 64 KB
    float*          vpart  = (float*)(ws + (6u << 20) + 65536);          // 64 KB
    float*          Mfull  = (float*)(ws + (6u << 20) + 131072);         // 64 KB
    float*          Mcorr  = (float*)(ws + (6u << 20) + 196608);         // 64 KB
    float*          mktotF = (float*)(ws + (6u << 20) + 262144);         // 1 KB
    float*          VtotF  = (float*)(ws + (6u << 20) + 263168);         // 1 KB

    void* args[] = {
        (void*)&feat, (void*)&Wq, (void*)&bq, (void*)&Wk, (void*)&bk,
        (void*)&Wv, (void*)&bv, (void*)&qsb, (void*)&ktb, (void*)&vtb,
        (void*)&kpart, (void*)&vpart, (void*)&Mfull, (void*)&Mcorr,
        (void*)&mktotF, (void*)&VtotF, (void*)&out
    };
    hipLaunchCooperativeKernel((void*)fused_kernel, dim3(256), dim3(256),
                               args, 0, stream);
}

// Round 11
// 88.448 us; speedup vs baseline: 1.8111x; 1.8111x over previous
//
#include <hip/hip_runtime.h>
#include <hip/hip_bf16.h>
#include <math.h>

#define SEQ 4096
#define HD  64
#define NBATCH 4

#define EM1   1.71828182845904523536f
#define INVD5 (1.0f/(4096.f + 5.f*EM1))
#define INVD4 (1.0f/(4096.f + 4.f*EM1))
#define INVD3 (1.0f/(4096.f + 3.f*EM1))

typedef __attribute__((ext_vector_type(8))) short short8;
typedef __attribute__((ext_vector_type(4))) float f32x4;

__device__ __forceinline__ f32x4 mfma16(short8 a, short8 b, f32x4 c) {
    return __builtin_amdgcn_mfma_f32_16x16x32_bf16(a, b, c, 0, 0, 0);
}

__device__ __forceinline__ short bfs(float x) {
    __hip_bfloat16 h = __float2bfloat16(x);
    return *(short*)&h;
}

__device__ __forceinline__ short8 pack8(float4 a, float4 b) {
    short8 r;
    r[0] = bfs(a.x); r[1] = bfs(a.y); r[2] = bfs(a.z); r[3] = bfs(a.w);
    r[4] = bfs(b.x); r[5] = bfs(b.y); r[6] = bfs(b.z); r[7] = bfs(b.w);
    return r;
}

__device__ __forceinline__ float blo(unsigned v) { return __uint_as_float(v << 16); }
__device__ __forceinline__ float bhi(unsigned v) { return __uint_as_float(v & 0xffff0000u); }
__device__ __forceinline__ float b2f(__hip_bfloat16 h) { return __bfloat162float(h); }

// ---------------------------------------------------------------------------
// Kernel 0: prepack W matrices to bf16 (Wq scaled by exact 0.125).
// grid 3 x 256 thr; 16 elems/thread.
// ---------------------------------------------------------------------------
__global__ __launch_bounds__(256) void wpack_kernel(
    const float* __restrict__ Wq, const float* __restrict__ Wk,
    const float* __restrict__ Wv, __hip_bfloat16* __restrict__ Wb)
{
    const int m = blockIdx.x, tid = threadIdx.x;
    const float* W = (m == 0) ? Wq : (m == 1) ? Wk : Wv;
    const float s = (m == 0) ? 0.125f : 1.f;
    const float* src = W + tid * 16;
    float4 a0 = *(const float4*)(src);
    float4 a1 = *(const float4*)(src + 4);
    float4 a2 = *(const float4*)(src + 8);
    float4 a3 = *(const float4*)(src + 12);
    a0.x*=s; a0.y*=s; a0.z*=s; a0.w*=s;
    a1.x*=s; a1.y*=s; a1.z*=s; a1.w*=s;
    a2.x*=s; a2.y*=s; a2.z*=s; a2.w*=s;
    a3.x*=s; a3.y*=s; a3.z*=s; a3.w*=s;
    __hip_bfloat16* dst = Wb + m * 4096 + tid * 16;
    *(short8*)(dst)     = pack8(a0, a1);
    *(short8*)(dst + 8) = pack8(a2, a3);
}

// ---------------------------------------------------------------------------
// Kernel 1: projections via MFMA.  512 blocks x 128 thr (2 waves, 32 rows).
// W pre-packed bf16 (Wq pre-scaled).  k/v transpose: transposed LDS writes
// (stride-72, 2-way = free), vector b128 reads, coalesced global stores.
// ---------------------------------------------------------------------------
__global__ __launch_bounds__(128) void proj_kernel(
    const float* __restrict__ feat, const __hip_bfloat16* __restrict__ Wb,
    const float* __restrict__ bq, const float* __restrict__ bk,
    const float* __restrict__ bv,
    __hip_bfloat16* __restrict__ qsb, __hip_bfloat16* __restrict__ ktb,
    __hip_bfloat16* __restrict__ vtb,
    float* __restrict__ kpart, float* __restrict__ vpart)
{
    __shared__ __hip_bfloat16 tscr[64 * 72];   // [h][32 t] transposed tile
    __shared__ float kred[2][64];

    const int tid  = threadIdx.x;
    const int wave = tid >> 6, lane = tid & 63;
    const int quad = lane >> 4, ln = lane & 15;
    const int R0 = blockIdx.x * 32;            // [0, B*S)
    const int b  = R0 >> 12;
    const int t0 = R0 & (SEQ - 1);

    short8 af0, af1;
    {
        const float* fp = feat + (size_t)(R0 + wave * 16 + ln) * HD + quad * 8;
        af0 = pack8(*(const float4*)(fp),      *(const float4*)(fp + 4));
        af1 = pack8(*(const float4*)(fp + 32), *(const float4*)(fp + 36));
    }

    const float* Bs[3] = {bq, bk, bv};

    #pragma unroll
    for (int m = 0; m < 3; ++m) {
        const __hip_bfloat16* W = Wb + m * 4096;
        const float* bias = Bs[m];
        #pragma unroll
        for (int ct = 0; ct < 4; ++ct) {
            const int col = ct * 16 + ln;
            const __hip_bfloat16* wp = W + col * 64 + quad * 8;
            short8 b0 = *(const short8*)(wp);
            short8 b1 = *(const short8*)(wp + 32);
            f32x4 c = {};
            c = mfma16(af0, b0, c);
            c = mfma16(af1, b1, c);

            if (m == 0) {
                const float bl = bias[col] * 0.125f;
                #pragma unroll
                for (int r = 0; r < 4; ++r)
                    qsb[(size_t)(R0 + wave * 16 + quad * 4 + r) * HD + col] =
                        __float2bfloat16(c[r] + bl);
            } else {
                const float bl = bias[col];
                float tot = c[0] + c[1] + c[2] + c[3];
                tot += __shfl_xor(tot, 16);
                tot += __shfl_xor(tot, 32);
                if (quad == 0) kred[wave][col] = tot;
                #pragma unroll
                for (int r = 0; r < 4; ++r)
                    tscr[col * 72 + wave * 16 + quad * 4 + r] =
                        __float2bfloat16(c[r] + bl);
            }
        }
        if (m > 0) {
            __syncthreads();
            if (tid < 64)
                ((m == 1) ? kpart : vpart)[(size_t)blockIdx.x * 64 + tid] =
                    kred[0][tid] + kred[1][tid] + 32.f * bias[tid];
            __hip_bfloat16* dst = (m == 1) ? ktb : vtb;
            #pragma unroll
            for (int i = 0; i < 2; ++i) {
                const int tsk = i * 128 + tid;     // 256 tasks: 64 h x 4 chunks
                const int hh = tsk >> 2, c8 = tsk & 3;
                short8 vv = *(const short8*)&tscr[hh * 72 + c8 * 8];
                *(short8*)(dst + ((size_t)(b * HD + hh)) * SEQ + t0 + c8 * 8) = vv;
            }
            __syncthreads();
        }
    }
}

// ---------------------------------------------------------------------------
// Kernel 2: Gpart[h1][h2] += sum_t k[t][h1]*locv5[t][h2] per 32-t chunk (MFMA),
// grid (128, 5): y<4 = batch, y==4/x<16 = correction slab.
// ---------------------------------------------------------------------------
__global__ __launch_bounds__(256) void mkernel(
    const __hip_bfloat16* __restrict__ ktb, const __hip_bfloat16* __restrict__ vtb,
    const float* __restrict__ kpart, const float* __restrict__ vpart,
    __hip_bfloat16* __restrict__ Mpart, float* __restrict__ Mcorr,
    __hip_bfloat16* __restrict__ MT, float* __restrict__ Vtot)
{
    __shared__ float vws[64 * 38];              // v window [h][t0-2..t0+34)
    __shared__ __hip_bfloat16 lvt[64 * 40];     // locv5^T [h][32 t]
    __shared__ float scr[4][64];
    __shared__ float ktl[64], vtl[64];
    __shared__ float lc[4][64], vv_e[4][64];

    const int tid = threadIdx.x;

    if (blockIdx.y == 4) {
        if (blockIdx.x >= 16) return;
        const int b = blockIdx.x >> 2, slab = blockIdx.x & 3;
        const int h = tid & 63, g = tid >> 6;

        if (slab == 0 || slab == 3) {
            float kp = 0.f;
            for (int j = 0; j < 32; ++j)
                kp += kpart[(size_t)(b * 128 + g * 32 + j) * 64 + h];
            scr[g][h] = kp;
            __syncthreads();
            if (tid < 64) ktl[tid] = scr[0][tid] + scr[1][tid] + scr[2][tid] + scr[3][tid];
        }
        if (slab == 0) {
            __syncthreads();
            if (tid < 64) {
                const int hh = tid;
                const float kt = ktl[hh];
                const __hip_bfloat16* kr = ktb + (size_t)(b * 64 + hh) * SEQ;
                const float e0 = b2f(kr[0]), e1 = b2f(kr[1]), e2 = b2f(kr[2]), e3 = b2f(kr[3]);
                const float f0 = b2f(kr[SEQ-4]), f1 = b2f(kr[SEQ-3]);
                const float f2 = b2f(kr[SEQ-2]), f3 = b2f(kr[SEQ-1]);
                const float Sint = 5.f*kt - 4.f*e0 - 3.f*e1 - 2.f*e2 - e3
                                 - f0 - 2.f*f1 - 3.f*f2 - 4.f*f3;
                const float SlocD = Sint * INVD5
                                  + (e0+e1+e2 + f1+f2+f3) * INVD3
                                  + (e0+e1+e2+e3 + f0+f1+f2+f3) * INVD4;
                const float mktot = kt * (4092.f*INVD5 + 2.f*INVD4 + 2.f*INVD3) + EM1 * SlocD;
                MT[(size_t)b * 5120 + 64 * 64 + hh] = __float2bfloat16(mktot);
            }
        } else if (slab == 1) {
            float vp = 0.f;
            for (int j = 0; j < 32; ++j)
                vp += vpart[(size_t)(b * 128 + g * 32 + j) * 64 + h];
            scr[g][h] = vp;
            __syncthreads();
            if (tid < 64)
                Vtot[b * 64 + tid] = scr[0][tid] + scr[1][tid] + scr[2][tid] + scr[3][tid];
        } else if (slab == 2) {
            for (int i = tid; i < 15 * 64; i += 256)
                MT[(size_t)b * 5120 + 65 * 64 + i] = __float2bfloat16(0.f);
        } else {
            __syncthreads();      // ktl ready
            {
                float vp = 0.f;
                for (int j = 0; j < 32; ++j)
                    vp += vpart[(size_t)(b * 128 + g * 32 + j) * 64 + h];
                scr[g][h] = vp;
            }
            __syncthreads();
            if (tid < 64) vtl[tid] = scr[0][tid] + scr[1][tid] + scr[2][tid] + scr[3][tid];
            if (tid < 64) {
                const int hh = tid;
                const __hip_bfloat16* kr = ktb + (size_t)(b * 64 + hh) * SEQ;
                const float e0 = b2f(kr[0]), e1 = b2f(kr[1]), e2 = b2f(kr[2]), e3 = b2f(kr[3]);
                const float f0 = b2f(kr[SEQ-4]), f1 = b2f(kr[SEQ-3]);
                const float f2 = b2f(kr[SEQ-2]), f3 = b2f(kr[SEQ-1]);
                lc[0][hh] = e0 + e1 + e2;
                lc[1][hh] = e0 + e1 + e2 + e3;
                lc[2][hh] = f0 + f1 + f2 + f3;
                lc[3][hh] = f1 + f2 + f3;
                const __hip_bfloat16* vr = vtb + (size_t)(b * 64 + hh) * SEQ;
                vv_e[0][hh] = b2f(vr[0]);
                vv_e[1][hh] = b2f(vr[1]);
                vv_e[2][hh] = b2f(vr[SEQ-2]);
                vv_e[3][hh] = b2f(vr[SEQ-1]);
            }
            __syncthreads();
            const float dd3 = INVD3 - INVD5, dd4 = INVD4 - INVD5;
            const int h1 = tid >> 2;
            const float l0 = lc[0][h1], l1 = lc[1][h1], l2 = lc[2][h1], l3 = lc[3][h1];
            const float kt1 = ktl[h1];
            #pragma unroll
            for (int j = 0; j < 16; ++j) {
                const int h2 = (tid & 3) * 16 + j;
                const float VD = INVD5 * vtl[h2]
                               + dd3 * (vv_e[0][h2] + vv_e[3][h2])
                               + dd4 * (vv_e[1][h2] + vv_e[2][h2]);
                Mcorr[(size_t)(b * 64 + h1) * 64 + h2] =
                    EM1 * (dd3 * (l0 * vv_e[0][h2] + l3 * vv_e[3][h2])
                         + dd4 * (l1 * vv_e[1][h2] + l2 * vv_e[2][h2]))
                    + kt1 * VD;
            }
        }
        return;
    }

    // ---------------- main GEMM chunk ----------------
    const int b = blockIdx.y, chunk = blockIdx.x;
    const int t0 = chunk * 32;

    for (int i = tid; i < 64 * 18; i += 256) {
        const int r = i / 18, c = i - r * 18;
        const int gt = t0 - 2 + c * 2;
        unsigned val = 0;
        if (gt >= 0 && gt <= SEQ - 2)
            val = *(const unsigned*)(vtb + (size_t)(b * 64 + r) * SEQ + gt);
        vws[r * 38 + c * 2]     = blo(val);
        vws[r * 38 + c * 2 + 1] = bhi(val);
    }
    __syncthreads();

    {
        const int h = tid & 63, g = tid >> 6;
        float w[12];
        #pragma unroll
        for (int j = 0; j < 12; ++j) w[j] = vws[h * 38 + g * 8 + j];
        short8 o;
        #pragma unroll
        for (int i = 0; i < 8; ++i)
            o[i] = bfs(w[i] + w[i+1] + w[i+2] + w[i+3] + w[i+4]);
        *(short8*)&lvt[h * 40 + g * 8] = o;
    }
    __syncthreads();

    const int wave = tid >> 6, lane = tid & 63, quad = lane >> 4, ln = lane & 15;
    short8 a = *(const short8*)(ktb + (size_t)(b * 64 + wave * 16 + ln) * SEQ
                                + t0 + quad * 8);
    f32x4 acc[4] = {};
    #pragma unroll
    for (int ct = 0; ct < 4; ++ct) {
        short8 bb = *(const short8*)&lvt[(ct * 16 + ln) * 40 + quad * 8];
        acc[ct] = mfma16(a, bb, acc[ct]);
    }
    __hip_bfloat16* mp = Mpart + (size_t)(b * 128 + chunk) * 4096;
    #pragma unroll
    for (int ct = 0; ct < 4; ++ct)
        #pragma unroll
        for (int r = 0; r < 4; ++r)
            mp[(wave * 16 + quad * 4 + r) * 64 + ct * 16 + ln] =
                __float2bfloat16(acc[ct][r]);
}

// ---------------------------------------------------------------------------
// Kernel 3: MT[h2][h1] = bf16(EM1*INVD5*sum_c Gpart + Mcorr[h1][h2]).
// ---------------------------------------------------------------------------
__global__ __launch_bounds__(256) void mreduce_kernel(
    const __hip_bfloat16* __restrict__ Mpart, const float* __restrict__ Mcorr,
    __hip_bfloat16* __restrict__ MT)
{
    __shared__ float red[4][64];
    const int b = blockIdx.y, h1 = blockIdx.x;
    const int tid = threadIdx.x;
    const int g = tid >> 6, h2 = tid & 63;

    float s = 0.f;
    for (int c = g * 32; c < g * 32 + 32; ++c)
        s += b2f(Mpart[(size_t)(b * 128 + c) * 4096 + h1 * 64 + h2]);
    red[g][h2] = s;
    __syncthreads();
    if (tid < 64) {
        const float m = (EM1 * INVD5) * (red[0][tid] + red[1][tid] + red[2][tid] + red[3][tid])
                      + Mcorr[(size_t)(b * 64 + h1) * 64 + tid];
        MT[(size_t)b * 5120 + tid * 64 + h1] = __float2bfloat16(m);
    }
}

// ---------------------------------------------------------------------------
// Kernel 4: out = (Vtot + qs*M) / (4096 + qs*mktot) via MFMA.  grid 1024 x 64.
// ---------------------------------------------------------------------------
__global__ __launch_bounds__(64) void out_kernel(
    const __hip_bfloat16* __restrict__ qsb, const __hip_bfloat16* __restrict__ MT,
    const float* __restrict__ Vtot, float* __restrict__ out)
{
    const int tid = threadIdx.x;
    const int quad = tid >> 4, ln = tid & 15;
    const int R0 = blockIdx.x * 16;
    const int b = R0 >> 12;

    short8 qa0, qa1;
    {
        const __hip_bfloat16* qp = qsb + (size_t)(R0 + ln) * HD + quad * 8;
        qa0 = *(const short8*)qp;
        qa1 = *(const short8*)(qp + 32);
    }

    const __hip_bfloat16* mtb = MT + (size_t)b * 5120;
    f32x4 acc[5] = {};
    #pragma unroll
    for (int ct = 0; ct < 5; ++ct) {
        short8 b0 = *(const short8*)(mtb + (ct * 16 + ln) * 64 + quad * 8);
        short8 b1 = *(const short8*)(mtb + (ct * 16 + ln) * 64 + 32 + quad * 8);
        acc[ct] = mfma16(qa0, b0, acc[ct]);
        acc[ct] = mfma16(qa1, b1, acc[ct]);
    }

    float vt[4];
    #pragma unroll
    for (int ct = 0; ct < 4; ++ct) vt[ct] = Vtot[b * 64 + ct * 16 + ln];

    float inv[4];
    #pragma unroll
    for (int r = 0; r < 4; ++r) {
        const float den = __shfl(acc[4][r], tid & 48);
        inv[r] = 1.f / (4096.f + den);
    }
    #pragma unroll
    for (int ct = 0; ct < 4; ++ct)
        #pragma unroll
        for (int r = 0; r < 4; ++r)
            out[(size_t)(R0 + quad * 4 + r) * HD + ct * 16 + ln] =
                (vt[ct] + acc[ct][r]) * inv[r];
}

// ---------------------------------------------------------------------------
extern "C" void kernel_launch(void* const* d_in, const int* in_sizes, int n_in,
                              void* d_out, int out_size, void* d_ws, size_t ws_size,
                              hipStream_t stream)
{
    const float* feat = (const float*)d_in[0];
    const float* Wq = (const float*)d_in[1];
    const float* bq = (const float*)d_in[2];
    const float* Wk = (const float*)d_in[3];
    const float* bk = (const float*)d_in[4];
    const float* Wv = (const float*)d_in[5];
    const float* bv = (const float*)d_in[6];
    float* out = (float*)d_out;

    char* ws = (char*)d_ws;
    __hip_bfloat16* qsb   = (__hip_bfloat16*)(ws + 0);                     // 2 MB
    __hip_bfloat16* ktb   = (__hip_bfloat16*)(ws + (2u << 20));            // 2 MB
    __hip_bfloat16* vtb   = (__hip_bfloat16*)(ws + (4u << 20));            // 2 MB
    float*          kpart = (float*)(ws + (6u << 20));                     // 128 KB
    float*          vpart = (float*)(ws + (6u << 20) + 262144);            // 128 KB
    __hip_bfloat16* Mpart = (__hip_bfloat16*)(ws + (6u << 20) + 524288);   // 4 MB
    float*          Mcorr = (float*)(ws + (10u << 20) + 524288);           // 64 KB
    __hip_bfloat16* MT    = (__hip_bfloat16*)(ws + (10u << 20) + 589824);  // 40 KB
    float*          Vtot  = (float*)(ws + (10u << 20) + 630784);           // 1 KB
    __hip_bfloat16* Wb    = (__hip_bfloat16*)(ws + (10u << 20) + 631808);  // 24 KB

    wpack_kernel<<<dim3(3), dim3(256), 0, stream>>>(Wq, Wk, Wv, Wb);
    proj_kernel<<<dim3(512), dim3(128), 0, stream>>>(
        feat, Wb, bq, bk, bv, qsb, ktb, vtb, kpart, vpart);
    mkernel<<<dim3(128, 5), dim3(256), 0, stream>>>(
        ktb, vtb, kpart, vpart, Mpart, Mcorr, MT, Vtot);
    mreduce_kernel<<<dim3(64, NBATCH), dim3(256), 0, stream>>>(Mpart, Mcorr, MT);
    out_kernel<<<dim3(1024), dim3(64), 0, stream>>>(qsb, MT, Vtot, out);
}